// Round 1
// baseline (440.647 us; speedup 1.0000x reference)
//
#include <hip/hip_runtime.h>
#include <math.h>

#define PATCH 16
#define BATCH 64
#define CIN 3
#define HH 224
#define WW 224
#define HO14 14
#define WO14 14
#define NPATCH (BATCH*HO14*WO14)   // 12544
#define KDIM 768                   // CIN*PATCH*PATCH
#define NOFF 512                   // 2*K
#define NOUT 768
#define KPTS 256
#define EPSF 1e-5f

__device__ __forceinline__ float gelu_exact(float v) {
    return 0.5f * v * (1.0f + erff(v * 0.70710678118654752440f));
}

// ---------------------------------------------------------------------------
// GEMM1: off[p][n] = sum_e patch[p][e] * offw[n][e] + offb[n]
//   patch[p][e] = x[b][c][ho*16+i][wo*16+j], e = c*256 + i*16 + j
// tile 64x64, BK=16, 256 threads, 4x4 micro-tile
// ---------------------------------------------------------------------------
__global__ __launch_bounds__(256) void gemm_offsets(
    const float* __restrict__ x, const float* __restrict__ offw,
    const float* __restrict__ offb, float* __restrict__ off)
{
    __shared__ float As[16][68];
    __shared__ float Bs[16][68];
    const int t  = threadIdx.x;
    const int tx = t & 15, ty = t >> 4;
    const int bm = blockIdx.x * 64, bn = blockIdx.y * 64;
    const int kk = tx, rr = ty;     // staging role: kk = k-within-step, rr = row group

    const float* xbase[4];
#pragma unroll
    for (int q = 0; q < 4; ++q) {
        int m = bm + rr + 16*q;
        int b = m / 196, rem = m % 196;
        int ho = rem / 14, wo = rem % 14;
        xbase[q] = x + (size_t)b*CIN*HH*WW + (size_t)(ho*PATCH)*WW + (size_t)(wo*PATCH);
    }

    float acc[4][4] = {};
    for (int k0 = 0; k0 < KDIM; k0 += 16) {
        int e = k0 + kk;
        int c = e >> 8, ii = (e >> 4) & 15, jj = e & 15;
        size_t xoff = (size_t)c*HH*WW + (size_t)ii*WW + jj;
#pragma unroll
        for (int q = 0; q < 4; ++q) {
            As[kk][rr + 16*q] = xbase[q][xoff];
            Bs[kk][rr + 16*q] = offw[(size_t)(bn + rr + 16*q)*KDIM + e];
        }
        __syncthreads();
#pragma unroll
        for (int ki = 0; ki < 16; ++ki) {
            float4 a4 = *(const float4*)&As[ki][ty*4];
            float4 b4 = *(const float4*)&Bs[ki][tx*4];
            float av[4] = {a4.x, a4.y, a4.z, a4.w};
            float bv[4] = {b4.x, b4.y, b4.z, b4.w};
#pragma unroll
            for (int im = 0; im < 4; ++im)
#pragma unroll
                for (int in = 0; in < 4; ++in)
                    acc[im][in] += av[im] * bv[in];
        }
        __syncthreads();
    }

#pragma unroll
    for (int im = 0; im < 4; ++im) {
        int m = bm + ty*4 + im;
        int n = bn + tx*4;
        float4 v;
        v.x = acc[im][0] + offb[n+0];
        v.y = acc[im][1] + offb[n+1];
        v.z = acc[im][2] + offb[n+2];
        v.w = acc[im][3] + offb[n+3];
        *(float4*)&off[(size_t)m*NOFF + n] = v;
    }
}

// ---------------------------------------------------------------------------
// Sampler: A2[p][c*256+k] = bilinear(x[b][c], py, px) with zero-pad OOB
// ---------------------------------------------------------------------------
__global__ __launch_bounds__(256) void sampler(
    const float* __restrict__ x, const float* __restrict__ off,
    float* __restrict__ A2)
{
    int p = blockIdx.x;
    int k = threadIdx.x;
    int b = p / 196, rem = p % 196;
    int ho = rem / 14, wo = rem % 14;

    float2 d = ((const float2*)off)[(size_t)p*KPTS + k];   // (dy, dx)
    float py = (float)(ho*PATCH + (k >> 4)) + d.x;
    float px = (float)(wo*PATCH + (k & 15)) + d.y;
    float fy = floorf(py), fx = floorf(px);
    float wy1 = py - fy, wx1 = px - fx;
    float wy0 = 1.f - wy1, wx0 = 1.f - wx1;
    int y0 = (int)fy, x0 = (int)fx;
    int y1 = y0 + 1, x1 = x0 + 1;
    bool oky0 = (y0 >= 0) & (y0 < HH);
    bool oky1 = (y1 >= 0) & (y1 < HH);
    bool okx0 = (x0 >= 0) & (x0 < WW);
    bool okx1 = (x1 >= 0) & (x1 < WW);
    int yc0 = min(max(y0, 0), HH-1), yc1 = min(max(y1, 0), HH-1);
    int xc0 = min(max(x0, 0), WW-1), xc1 = min(max(x1, 0), WW-1);
    float w00 = wy0*wx0, w01 = wy0*wx1, w10 = wy1*wx0, w11 = wy1*wx1;

    const float* xb = x + (size_t)b*CIN*HH*WW;
#pragma unroll
    for (int c = 0; c < CIN; ++c) {
        const float* xc = xb + (size_t)c*HH*WW;
        float v00 = (oky0 && okx0) ? xc[(size_t)yc0*WW + xc0] : 0.f;
        float v01 = (oky0 && okx1) ? xc[(size_t)yc0*WW + xc1] : 0.f;
        float v10 = (oky1 && okx0) ? xc[(size_t)yc1*WW + xc0] : 0.f;
        float v11 = (oky1 && okx1) ? xc[(size_t)yc1*WW + xc1] : 0.f;
        float v = v00*w00 + v01*w01 + v10*w10 + v11*w11;
        A2[(size_t)p*KDIM + c*KPTS + k] = v;
    }
}

// ---------------------------------------------------------------------------
// GEMM2: y[p][o] = sum_e A2[p][e] * dconvw[o][e]   (y == d_out layout!)
// ---------------------------------------------------------------------------
__global__ __launch_bounds__(256) void gemm_deform(
    const float* __restrict__ A, const float* __restrict__ Bw,
    float* __restrict__ C)
{
    __shared__ float As[16][68];
    __shared__ float Bs[16][68];
    const int t  = threadIdx.x;
    const int tx = t & 15, ty = t >> 4;
    const int bm = blockIdx.x * 64, bn = blockIdx.y * 64;
    const int kk = tx, rr = ty;

    float acc[4][4] = {};
    for (int k0 = 0; k0 < KDIM; k0 += 16) {
        int e = k0 + kk;
#pragma unroll
        for (int q = 0; q < 4; ++q) {
            As[kk][rr + 16*q] = A [(size_t)(bm + rr + 16*q)*KDIM + e];
            Bs[kk][rr + 16*q] = Bw[(size_t)(bn + rr + 16*q)*KDIM + e];
        }
        __syncthreads();
#pragma unroll
        for (int ki = 0; ki < 16; ++ki) {
            float4 a4 = *(const float4*)&As[ki][ty*4];
            float4 b4 = *(const float4*)&Bs[ki][tx*4];
            float av[4] = {a4.x, a4.y, a4.z, a4.w};
            float bv[4] = {b4.x, b4.y, b4.z, b4.w};
#pragma unroll
            for (int im = 0; im < 4; ++im)
#pragma unroll
                for (int in = 0; in < 4; ++in)
                    acc[im][in] += av[im] * bv[in];
        }
        __syncthreads();
    }

#pragma unroll
    for (int im = 0; im < 4; ++im) {
        int m = bm + ty*4 + im;
        float4 v = make_float4(acc[im][0], acc[im][1], acc[im][2], acc[im][3]);
        *(float4*)&C[(size_t)m*NOUT + bn + tx*4] = v;
    }
}

// ---------------------------------------------------------------------------
// BN stats, two-phase deterministic
// ---------------------------------------------------------------------------
__global__ __launch_bounds__(256) void bn_partial(
    const float* __restrict__ y, float* __restrict__ psum, float* __restrict__ psq)
{
    int t = threadIdx.x;
    int r0 = blockIdx.x * 64;
    float s0=0,s1=0,s2=0,q0=0,q1=0,q2=0;
    for (int r = r0; r < r0 + 64; ++r) {
        const float* row = y + (size_t)r*NOUT;
        float v0 = row[t], v1 = row[t+256], v2 = row[t+512];
        s0 += v0; q0 += v0*v0;
        s1 += v1; q1 += v1*v1;
        s2 += v2; q2 += v2*v2;
    }
    float* ps = psum + (size_t)blockIdx.x*NOUT;
    float* pq = psq  + (size_t)blockIdx.x*NOUT;
    ps[t] = s0; ps[t+256] = s1; ps[t+512] = s2;
    pq[t] = q0; pq[t+256] = q1; pq[t+512] = q2;
}

__global__ __launch_bounds__(256) void bn_final(
    const float* __restrict__ psum, const float* __restrict__ psq,
    const float* __restrict__ gamma, const float* __restrict__ beta,
    float* __restrict__ scale, float* __restrict__ shift)
{
    int o = blockIdx.x*256 + threadIdx.x;   // 0..767
    float s = 0.f, q = 0.f;
    for (int i = 0; i < NPATCH/64; ++i) {   // 196 partials
        s += psum[(size_t)i*NOUT + o];
        q += psq [(size_t)i*NOUT + o];
    }
    float mean = s * (1.0f/(float)NPATCH);
    float var  = q * (1.0f/(float)NPATCH) - mean*mean;
    float inv  = 1.0f / sqrtf(var + EPSF);
    float sc   = gamma[o] * inv;
    scale[o] = sc;
    shift[o] = beta[o] - mean*sc;
}

// ---------------------------------------------------------------------------
// In-place normalize + exact GELU on d_out (y layout == out layout)
// ---------------------------------------------------------------------------
__global__ __launch_bounds__(256) void norm_gelu(
    float* __restrict__ y, const float* __restrict__ scale,
    const float* __restrict__ shift)
{
    __shared__ float ssc[NOUT], ssh[NOUT];
    for (int i = threadIdx.x; i < NOUT; i += 256) { ssc[i] = scale[i]; ssh[i] = shift[i]; }
    __syncthreads();
    const size_t total4 = (size_t)NPATCH * NOUT / 4;
    for (size_t i = (size_t)blockIdx.x*256 + threadIdx.x; i < total4;
         i += (size_t)gridDim.x*256) {
        float4 v = ((float4*)y)[i];
        int og = (int)(i % (NOUT/4));       // float4 group within a row
        float4 sc = ((const float4*)ssc)[og];
        float4 sh = ((const float4*)ssh)[og];
        v.x = gelu_exact(v.x*sc.x + sh.x);
        v.y = gelu_exact(v.y*sc.y + sh.y);
        v.z = gelu_exact(v.z*sc.z + sh.z);
        v.w = gelu_exact(v.w*sc.w + sh.w);
        ((float4*)y)[i] = v;
    }
}

// ---------------------------------------------------------------------------
extern "C" void kernel_launch(void* const* d_in, const int* in_sizes, int n_in,
                              void* d_out, int out_size, void* d_ws, size_t ws_size,
                              hipStream_t stream)
{
    const float* x      = (const float*)d_in[0];
    const float* offw   = (const float*)d_in[1];
    const float* offb   = (const float*)d_in[2];
    const float* dconvw = (const float*)d_in[3];
    const float* gamma  = (const float*)d_in[4];
    const float* beta   = (const float*)d_in[5];
    float* out = (float*)d_out;

    float* wsf   = (float*)d_ws;
    float* A2    = wsf;                       // 12544*768 = 9,633,792 floats
    float* off   = A2 + (size_t)NPATCH*KDIM;  // 12544*512 = 6,422,528 floats
    float* psum  = off + (size_t)NPATCH*NOFF; // 196*768
    float* psq   = psum + 196*NOUT;
    float* scale = psq  + 196*NOUT;
    float* shift = scale + NOUT;

    gemm_offsets<<<dim3(NPATCH/64, NOFF/64), 256, 0, stream>>>(x, offw, offb, off);
    sampler<<<NPATCH, 256, 0, stream>>>(x, off, A2);
    gemm_deform<<<dim3(NPATCH/64, NOUT/64), 256, 0, stream>>>(A2, dconvw, out);
    bn_partial<<<NPATCH/64, 256, 0, stream>>>(out, psum, psq);
    bn_final<<<3, 256, 0, stream>>>(psum, psq, gamma, beta, scale, shift);
    norm_gelu<<<2048, 256, 0, stream>>>(out, scale, shift);
}

// Round 2
// 143.018 us; speedup vs baseline: 3.0811x; 3.0811x over previous
//
#include <hip/hip_runtime.h>
#include <math.h>

#define PATCH 16
#define BATCH 64
#define CIN 3
#define HH 224
#define WW 224
#define NPATCH (BATCH*14*14)       // 12544
#define KDIM 768                   // CIN*PATCH*PATCH
#define NOFF 512                   // 2*K
#define NOUT 768
#define KPTS 256
#define EPSF 1e-5f
#define CHW (CIN*HH*WW)            // 150528
#define HWX (HH*WW)                // 50176

using short8 = __attribute__((ext_vector_type(8))) short;
using f32x4  = __attribute__((ext_vector_type(4))) float;

#define GLOAD16(g, l) __builtin_amdgcn_global_load_lds( \
    (const __attribute__((address_space(1))) void*)(g), \
    (__attribute__((address_space(3))) void*)(l), 16, 0, 0)

__device__ __forceinline__ unsigned short f2bf(float f) {
    unsigned int u = __float_as_uint(f);
    u = (u + 0x7fffu + ((u >> 16) & 1u)) >> 16;   // RNE
    return (unsigned short)u;
}
__device__ __forceinline__ float gelu_exact(float v) {
    return 0.5f * v * (1.0f + erff(v * 0.70710678118654752440f));
}

// ---------------------------------------------------------------------------
// fp32 -> bf16 bulk convert (vectorized float4 -> ushort4)
// ---------------------------------------------------------------------------
__global__ __launch_bounds__(256) void cvt_bf16(
    const float* __restrict__ in, unsigned short* __restrict__ out, int n4)
{
    int i = blockIdx.x * 256 + threadIdx.x;
    if (i >= n4) return;
    float4 v = ((const float4*)in)[i];
    ushort4 o = make_ushort4(f2bf(v.x), f2bf(v.y), f2bf(v.z), f2bf(v.w));
    ((ushort4*)out)[i] = o;
}

// ---------------------------------------------------------------------------
// GEMM1 (MFMA): off[p][n] = patch(xbf)[p][:] . offw[n][:] + offb[n]  -> bf16
// 128x128 tile, BK=32, 4 waves, global_load_lds staging
// ---------------------------------------------------------------------------
__global__ __launch_bounds__(256) void gemm_offsets(
    const unsigned short* __restrict__ xbf, const unsigned short* __restrict__ Bw,
    const float* __restrict__ offb, unsigned short* __restrict__ off)
{
    __shared__ unsigned short As[128*32];
    __shared__ unsigned short Bs[128*32];
    const int t = threadIdx.x;
    const int lane = t & 63;
    const int w = t >> 6, wr = w >> 1, wc = w & 1;
    const int bm = blockIdx.x * 128, bn = blockIdx.y * 128;
    const int rq = t >> 2;           // 0..63 (row within half-tile)
    const int ks = (t & 3) << 3;     // k-slot {0,8,16,24}

    // patch base pointers for the two staged rows this thread owns
    const unsigned short* aBase[2];
#pragma unroll
    for (int q = 0; q < 2; ++q) {
        int p = bm + q*64 + rq;
        int b = p / 196, rem = p % 196;
        int ho = rem / 14, wo = rem % 14;
        aBase[q] = xbf + (size_t)b*CHW + (size_t)(ho*PATCH)*WW + (size_t)(wo*PATCH);
    }
    const unsigned short* bSrc0 = Bw + (size_t)(bn + rq)*KDIM + ks;
    const unsigned short* bSrc1 = Bw + (size_t)(bn + 64 + rq)*KDIM + ks;
    unsigned short* aDst0 = As + t*8;
    unsigned short* aDst1 = As + 2048 + t*8;
    unsigned short* bDst0 = Bs + t*8;
    unsigned short* bDst1 = Bs + 2048 + t*8;

    const int row_a = wr*64 + (lane & 15);
    const int row_b = wc*64 + (lane & 15);
    const int kloc = (lane >> 4) * 8;

    f32x4 acc[4][4] = {};
    for (int k0 = 0; k0 < KDIM; k0 += 32) {
        int e = k0 + ks;
        int c = e >> 8, ii = (e >> 4) & 15, jj = e & 15;
        size_t xo = (size_t)c*HWX + (size_t)ii*WW + jj;
        GLOAD16(aBase[0] + xo, aDst0);
        GLOAD16(aBase[1] + xo, aDst1);
        GLOAD16(bSrc0 + k0, bDst0);
        GLOAD16(bSrc1 + k0, bDst1);
        __syncthreads();
        short8 af[4], bf_[4];
#pragma unroll
        for (int m = 0; m < 4; ++m)
            af[m] = *(const short8*)&As[(row_a + m*16)*32 + kloc];
#pragma unroll
        for (int n = 0; n < 4; ++n)
            bf_[n] = *(const short8*)&Bs[(row_b + n*16)*32 + kloc];
#pragma unroll
        for (int m = 0; m < 4; ++m)
#pragma unroll
            for (int n = 0; n < 4; ++n)
                acc[m][n] = __builtin_amdgcn_mfma_f32_16x16x32_bf16(af[m], bf_[n], acc[m][n], 0, 0, 0);
        __syncthreads();
    }

    const int col0 = bn + wc*64 + (lane & 15);
    const int r0 = (lane >> 4) * 4;
#pragma unroll
    for (int m = 0; m < 4; ++m) {
        int grow = bm + wr*64 + m*16 + r0;
#pragma unroll
        for (int n = 0; n < 4; ++n) {
            int gcol = col0 + n*16;
            float bias = offb[gcol];
#pragma unroll
            for (int r = 0; r < 4; ++r)
                off[(size_t)(grow + r)*NOFF + gcol] = f2bf(acc[m][n][r] + bias);
        }
    }
}

// ---------------------------------------------------------------------------
// Sampler: A2bf[p][c*256+k] = bilinear(x[b][c], py, px), zero-pad OOB
// ---------------------------------------------------------------------------
__global__ __launch_bounds__(256) void sampler(
    const float* __restrict__ x, const unsigned int* __restrict__ offu,
    unsigned short* __restrict__ A2)
{
    int p = blockIdx.x;
    int k = threadIdx.x;
    int b = p / 196, rem = p % 196;
    int ho = rem / 14, wo = rem % 14;

    unsigned int d2 = offu[(size_t)p*KPTS + k];          // lo=dy, hi=dx (bf16)
    float dy = __uint_as_float((d2 & 0xffffu) << 16);
    float dx = __uint_as_float(d2 & 0xffff0000u);
    float py = (float)(ho*PATCH + (k >> 4)) + dy;
    float px = (float)(wo*PATCH + (k & 15)) + dx;
    float fy = floorf(py), fx = floorf(px);
    float wy1 = py - fy, wx1 = px - fx;
    float wy0 = 1.f - wy1, wx0 = 1.f - wx1;
    int y0 = (int)fy, x0 = (int)fx;
    int y1 = y0 + 1, x1 = x0 + 1;
    bool oky0 = (y0 >= 0) & (y0 < HH);
    bool oky1 = (y1 >= 0) & (y1 < HH);
    bool okx0 = (x0 >= 0) & (x0 < WW);
    bool okx1 = (x1 >= 0) & (x1 < WW);
    int yc0 = min(max(y0, 0), HH-1), yc1 = min(max(y1, 0), HH-1);
    int xc0 = min(max(x0, 0), WW-1), xc1 = min(max(x1, 0), WW-1);
    float w00 = wy0*wx0, w01 = wy0*wx1, w10 = wy1*wx0, w11 = wy1*wx1;

    const float* xb = x + (size_t)b*CHW;
#pragma unroll
    for (int c = 0; c < CIN; ++c) {
        const float* xc = xb + (size_t)c*HWX;
        float v00 = (oky0 && okx0) ? xc[(size_t)yc0*WW + xc0] : 0.f;
        float v01 = (oky0 && okx1) ? xc[(size_t)yc0*WW + xc1] : 0.f;
        float v10 = (oky1 && okx0) ? xc[(size_t)yc1*WW + xc0] : 0.f;
        float v11 = (oky1 && okx1) ? xc[(size_t)yc1*WW + xc1] : 0.f;
        float v = v00*w00 + v01*w01 + v10*w10 + v11*w11;
        A2[(size_t)p*KDIM + c*KPTS + k] = f2bf(v);
    }
}

// ---------------------------------------------------------------------------
// GEMM2 (MFMA): y[p][o] = A2[p][:] . dconvw[o][:]  (y == d_out layout, fp32)
// ---------------------------------------------------------------------------
__global__ __launch_bounds__(256) void gemm_deform(
    const unsigned short* __restrict__ A, const unsigned short* __restrict__ Bw,
    float* __restrict__ C)
{
    __shared__ unsigned short As[128*32];
    __shared__ unsigned short Bs[128*32];
    const int t = threadIdx.x;
    const int lane = t & 63;
    const int w = t >> 6, wr = w >> 1, wc = w & 1;
    const int bm = blockIdx.x * 128, bn = blockIdx.y * 128;
    const int rq = t >> 2;
    const int ks = (t & 3) << 3;

    const unsigned short* aSrc0 = A + (size_t)(bm + rq)*KDIM + ks;
    const unsigned short* aSrc1 = A + (size_t)(bm + 64 + rq)*KDIM + ks;
    const unsigned short* bSrc0 = Bw + (size_t)(bn + rq)*KDIM + ks;
    const unsigned short* bSrc1 = Bw + (size_t)(bn + 64 + rq)*KDIM + ks;
    unsigned short* aDst0 = As + t*8;
    unsigned short* aDst1 = As + 2048 + t*8;
    unsigned short* bDst0 = Bs + t*8;
    unsigned short* bDst1 = Bs + 2048 + t*8;

    const int row_a = wr*64 + (lane & 15);
    const int row_b = wc*64 + (lane & 15);
    const int kloc = (lane >> 4) * 8;

    f32x4 acc[4][4] = {};
    for (int k0 = 0; k0 < KDIM; k0 += 32) {
        GLOAD16(aSrc0 + k0, aDst0);
        GLOAD16(aSrc1 + k0, aDst1);
        GLOAD16(bSrc0 + k0, bDst0);
        GLOAD16(bSrc1 + k0, bDst1);
        __syncthreads();
        short8 af[4], bf_[4];
#pragma unroll
        for (int m = 0; m < 4; ++m)
            af[m] = *(const short8*)&As[(row_a + m*16)*32 + kloc];
#pragma unroll
        for (int n = 0; n < 4; ++n)
            bf_[n] = *(const short8*)&Bs[(row_b + n*16)*32 + kloc];
#pragma unroll
        for (int m = 0; m < 4; ++m)
#pragma unroll
            for (int n = 0; n < 4; ++n)
                acc[m][n] = __builtin_amdgcn_mfma_f32_16x16x32_bf16(af[m], bf_[n], acc[m][n], 0, 0, 0);
        __syncthreads();
    }

    const int col0 = bn + wc*64 + (lane & 15);
    const int r0 = (lane >> 4) * 4;
#pragma unroll
    for (int m = 0; m < 4; ++m) {
        int grow = bm + wr*64 + m*16 + r0;
#pragma unroll
        for (int n = 0; n < 4; ++n) {
            int gcol = col0 + n*16;
#pragma unroll
            for (int r = 0; r < 4; ++r)
                C[(size_t)(grow + r)*NOUT + gcol] = acc[m][n][r];
        }
    }
}

// ---------------------------------------------------------------------------
// BN stats, two-phase deterministic
// ---------------------------------------------------------------------------
__global__ __launch_bounds__(256) void bn_partial(
    const float* __restrict__ y, float* __restrict__ psum, float* __restrict__ psq)
{
    int t = threadIdx.x;
    int r0 = blockIdx.x * 64;
    float s0=0,s1=0,s2=0,q0=0,q1=0,q2=0;
    for (int r = r0; r < r0 + 64; ++r) {
        const float* row = y + (size_t)r*NOUT;
        float v0 = row[t], v1 = row[t+256], v2 = row[t+512];
        s0 += v0; q0 += v0*v0;
        s1 += v1; q1 += v1*v1;
        s2 += v2; q2 += v2*v2;
    }
    float* ps = psum + (size_t)blockIdx.x*NOUT;
    float* pq = psq  + (size_t)blockIdx.x*NOUT;
    ps[t] = s0; ps[t+256] = s1; ps[t+512] = s2;
    pq[t] = q0; pq[t+256] = q1; pq[t+512] = q2;
}

__global__ __launch_bounds__(256) void bn_final(
    const float* __restrict__ psum, const float* __restrict__ psq,
    const float* __restrict__ gamma, const float* __restrict__ beta,
    float* __restrict__ scale, float* __restrict__ shift)
{
    int o = blockIdx.x*256 + threadIdx.x;
    float s = 0.f, q = 0.f;
    for (int i = 0; i < NPATCH/64; ++i) {
        s += psum[(size_t)i*NOUT + o];
        q += psq [(size_t)i*NOUT + o];
    }
    float mean = s * (1.0f/(float)NPATCH);
    float var  = q * (1.0f/(float)NPATCH) - mean*mean;
    float inv  = 1.0f / sqrtf(var + EPSF);
    float sc   = gamma[o] * inv;
    scale[o] = sc;
    shift[o] = beta[o] - mean*sc;
}

// ---------------------------------------------------------------------------
// In-place normalize + exact GELU on d_out
// ---------------------------------------------------------------------------
__global__ __launch_bounds__(256) void norm_gelu(
    float* __restrict__ y, const float* __restrict__ scale,
    const float* __restrict__ shift)
{
    __shared__ float ssc[NOUT], ssh[NOUT];
    for (int i = threadIdx.x; i < NOUT; i += 256) { ssc[i] = scale[i]; ssh[i] = shift[i]; }
    __syncthreads();
    const size_t total4 = (size_t)NPATCH * NOUT / 4;
    for (size_t i = (size_t)blockIdx.x*256 + threadIdx.x; i < total4;
         i += (size_t)gridDim.x*256) {
        float4 v = ((float4*)y)[i];
        int og = (int)(i % (NOUT/4));
        float4 sc = ((const float4*)ssc)[og];
        float4 sh = ((const float4*)ssh)[og];
        v.x = gelu_exact(v.x*sc.x + sh.x);
        v.y = gelu_exact(v.y*sc.y + sh.y);
        v.z = gelu_exact(v.z*sc.z + sh.z);
        v.w = gelu_exact(v.w*sc.w + sh.w);
        ((float4*)y)[i] = v;
    }
}

// ---------------------------------------------------------------------------
extern "C" void kernel_launch(void* const* d_in, const int* in_sizes, int n_in,
                              void* d_out, int out_size, void* d_ws, size_t ws_size,
                              hipStream_t stream)
{
    const float* x      = (const float*)d_in[0];
    const float* offw   = (const float*)d_in[1];
    const float* offb   = (const float*)d_in[2];
    const float* dconvw = (const float*)d_in[3];
    const float* gamma  = (const float*)d_in[4];
    const float* beta   = (const float*)d_in[5];
    float* out = (float*)d_out;

    const int NX = BATCH*CHW;           // 9,633,792
    const int NW1 = NOFF*KDIM;          // 393,216
    const int NW2 = NOUT*KDIM;          // 589,824

    unsigned short* xbf   = (unsigned short*)d_ws;
    unsigned short* wbf1  = xbf  + (size_t)NX;
    unsigned short* wbf2  = wbf1 + (size_t)NW1;
    unsigned short* A2    = wbf2 + (size_t)NW2;                 // NPATCH*KDIM
    unsigned short* off   = A2   + (size_t)NPATCH*KDIM;         // NPATCH*NOFF
    float* fscratch = (float*)(off + (size_t)NPATCH*NOFF);
    float* psum  = fscratch;            // 196*768
    float* psq   = psum + 196*NOUT;
    float* scale = psq  + 196*NOUT;
    float* shift = scale + NOUT;

    cvt_bf16<<<(NX/4 + 255)/256, 256, 0, stream>>>(x, xbf, NX/4);
    cvt_bf16<<<(NW1/4 + 255)/256, 256, 0, stream>>>(offw, wbf1, NW1/4);
    cvt_bf16<<<(NW2/4 + 255)/256, 256, 0, stream>>>(dconvw, wbf2, NW2/4);

    gemm_offsets<<<dim3(NPATCH/128, NOFF/128), 256, 0, stream>>>(xbf, wbf1, offb, off);
    sampler<<<NPATCH, 256, 0, stream>>>(x, (const unsigned int*)off, A2);
    gemm_deform<<<dim3(NPATCH/128, NOUT/128), 256, 0, stream>>>(A2, wbf2, out);
    bn_partial<<<NPATCH/64, 256, 0, stream>>>(out, psum, psq);
    bn_final<<<3, 256, 0, stream>>>(psum, psq, gamma, beta, scale, shift);
    norm_gelu<<<2048, 256, 0, stream>>>(out, scale, shift);
}

// Round 5
// 118.030 us; speedup vs baseline: 3.7334x; 1.2117x over previous
//
#include <hip/hip_runtime.h>
#include <math.h>

#define PATCH 16
#define BATCH 64
#define CIN 3
#define HH 224
#define WW 224
#define NPATCH (BATCH*14*14)       // 12544
#define KDIM 768                   // CIN*PATCH*PATCH
#define NOFF 512                   // 2*K
#define NOUT 768
#define KPTS 256
#define EPSF 1e-5f
#define CHW (CIN*HH*WW)            // 150528
#define HWX (HH*WW)                // 50176
#define NRB (NPATCH/128)           // 98 row blocks

using short8 = __attribute__((ext_vector_type(8))) short;
using f32x4  = __attribute__((ext_vector_type(4))) float;

#define GLOAD16(g, l) __builtin_amdgcn_global_load_lds( \
    (const __attribute__((address_space(1))) void*)(g), \
    (__attribute__((address_space(3))) void*)(l), 16, 0, 0)

__device__ __forceinline__ unsigned short f2bf(float f) {
    unsigned int u = __float_as_uint(f);
    u = (u + 0x7fffu + ((u >> 16) & 1u)) >> 16;   // RNE
    return (unsigned short)u;
}
__device__ __forceinline__ float bf2f(unsigned short h) {
    return __uint_as_float(((unsigned int)h) << 16);
}
__device__ __forceinline__ float gelu_exact(float v) {
    return 0.5f * v * (1.0f + erff(v * 0.70710678118654752440f));
}

// ---------------------------------------------------------------------------
// fp32 -> bf16 bulk convert
// ---------------------------------------------------------------------------
__global__ __launch_bounds__(256) void cvt_bf16(
    const float* __restrict__ in, unsigned short* __restrict__ out, int n4)
{
    int i = blockIdx.x * 256 + threadIdx.x;
    if (i >= n4) return;
    float4 v = ((const float4*)in)[i];
    ushort4 o = make_ushort4(f2bf(v.x), f2bf(v.y), f2bf(v.z), f2bf(v.w));
    ((ushort4*)out)[i] = o;
}

// ---------------------------------------------------------------------------
// GEMM1 (MFMA, depth-2 pipelined): off[p][n] = patch(xbf)[p][:].offw[n][:]+b
// grid: 392 blocks (98 row x 4 col), XCD-swizzled (392%8==0)
// LDS swizzle: chunk ^= row bits[2:1] (2-bit XOR involution)
// RACE FIX: lgkmcnt(0) drained before every s_barrier (raw barrier lacks
// __syncthreads' implicit LDS drain; 3-slot rotation has reuse distance 1).
// ---------------------------------------------------------------------------
__global__ __launch_bounds__(256) void gemm_offsets(
    const unsigned short* __restrict__ xbf, const unsigned short* __restrict__ Bw,
    const float* __restrict__ offb, unsigned short* __restrict__ off)
{
    __shared__ unsigned short lds[3*8192];
    const int t = threadIdx.x;
    const int lane = t & 63;
    const int w = t >> 6, wr = w >> 1, wc = w & 1;

    // XCD swizzle: 392 = 8*49
    int bid = blockIdx.x;
    int idx = (bid & 7)*49 + (bid >> 3);
    const int bm = (idx >> 2) * 128, bn = (idx & 3) * 128;

    const int rq = t >> 2;
    const int ksw = (((t & 3) ^ ((t >> 3) & 3)) << 3);   // swizzled k-chunk (shorts)

    const unsigned short* aBase0;
    const unsigned short* aBase1;
    {
        int p0 = bm + rq,      b0 = p0/196, r0 = p0%196;
        int p1 = bm + 64 + rq, b1 = p1/196, r1 = p1%196;
        aBase0 = xbf + (size_t)b0*CHW + (size_t)((r0/14)*PATCH)*WW + (size_t)((r0%14)*PATCH);
        aBase1 = xbf + (size_t)b1*CHW + (size_t)((r1/14)*PATCH)*WW + (size_t)((r1%14)*PATCH);
    }
    const unsigned short* bS0 = Bw + (size_t)(bn + rq)*KDIM + ksw;
    const unsigned short* bS1 = Bw + (size_t)(bn + 64 + rq)*KDIM + ksw;

    const int row_a = wr*64 + (lane & 15);
    const int row_b = wc*64 + (lane & 15);
    const int klocs = (((lane >> 4) ^ ((lane >> 1) & 3)) << 3);

#define STG1(slot, k0) do { \
        unsigned short* d = lds + (slot)*8192 + t*8; \
        int e = (k0) + ksw; \
        size_t xo = (size_t)(e >> 8)*HWX + (size_t)((e >> 4) & 15)*WW + (e & 15); \
        GLOAD16(aBase0 + xo, d); \
        GLOAD16(aBase1 + xo, d + 2048); \
        GLOAD16(bS0 + (k0), d + 4096); \
        GLOAD16(bS1 + (k0), d + 6144); \
    } while(0)

    f32x4 acc[4][4] = {};
    STG1(0, 0); STG1(1, 32);
    asm volatile("s_waitcnt vmcnt(4)" ::: "memory");
    __builtin_amdgcn_s_barrier();
#pragma unroll
    for (int it = 0; it < 24; ++it) {
        if (it + 2 < 24) STG1((it+2)%3, (it+2)*32);
        const unsigned short* As_ = lds + (it%3)*8192;
        const unsigned short* Bs_ = As_ + 4096;
        short8 af[4], bv[4];
#pragma unroll
        for (int m = 0; m < 4; ++m) af[m] = *(const short8*)&As_[(row_a + m*16)*32 + klocs];
#pragma unroll
        for (int n = 0; n < 4; ++n) bv[n] = *(const short8*)&Bs_[(row_b + n*16)*32 + klocs];
#pragma unroll
        for (int m = 0; m < 4; ++m)
#pragma unroll
            for (int n = 0; n < 4; ++n)
                acc[m][n] = __builtin_amdgcn_mfma_f32_16x16x32_bf16(af[m], bv[n], acc[m][n], 0, 0, 0);
        if (it < 22) { asm volatile("s_waitcnt vmcnt(4) lgkmcnt(0)" ::: "memory"); __builtin_amdgcn_s_barrier(); }
        else if (it == 22) { asm volatile("s_waitcnt vmcnt(0) lgkmcnt(0)" ::: "memory"); __builtin_amdgcn_s_barrier(); }
    }
#undef STG1

    const int col0 = bn + wc*64 + (lane & 15);
    const int r0 = (lane >> 4) * 4;
#pragma unroll
    for (int m = 0; m < 4; ++m) {
        int grow = bm + wr*64 + m*16 + r0;
#pragma unroll
        for (int n = 0; n < 4; ++n) {
            int gcol = col0 + n*16;
            float bias = offb[gcol];
#pragma unroll
            for (int r = 0; r < 4; ++r)
                off[(size_t)(grow + r)*NOFF + gcol] = f2bf(acc[m][n][r] + bias);
        }
    }
}

// ---------------------------------------------------------------------------
// Sampler: A2bf[p][c*256+k] = bilinear(xbf[b][c], py, px), zero-pad OOB
// ---------------------------------------------------------------------------
__global__ __launch_bounds__(256) void sampler(
    const unsigned short* __restrict__ xbf, const unsigned int* __restrict__ offu,
    unsigned short* __restrict__ A2)
{
    int p = blockIdx.x;
    int k = threadIdx.x;
    int b = p / 196, rem = p % 196;
    int ho = rem / 14, wo = rem % 14;

    unsigned int d2 = offu[(size_t)p*KPTS + k];          // lo=dy, hi=dx (bf16)
    float dy = __uint_as_float((d2 & 0xffffu) << 16);
    float dx = __uint_as_float(d2 & 0xffff0000u);
    float py = (float)(ho*PATCH + (k >> 4)) + dy;
    float px = (float)(wo*PATCH + (k & 15)) + dx;
    float fy = floorf(py), fx = floorf(px);
    float wy1 = py - fy, wx1 = px - fx;
    float wy0 = 1.f - wy1, wx0 = 1.f - wx1;
    int y0 = (int)fy, x0 = (int)fx;
    int y1 = y0 + 1, x1 = x0 + 1;
    bool oky0 = (y0 >= 0) & (y0 < HH);
    bool oky1 = (y1 >= 0) & (y1 < HH);
    bool okx0 = (x0 >= 0) & (x0 < WW);
    bool okx1 = (x1 >= 0) & (x1 < WW);
    int yc0 = min(max(y0, 0), HH-1), yc1 = min(max(y1, 0), HH-1);
    int xc0 = min(max(x0, 0), WW-1), xc1 = min(max(x1, 0), WW-1);
    float w00 = wy0*wx0, w01 = wy0*wx1, w10 = wy1*wx0, w11 = wy1*wx1;

    const unsigned short* xb = xbf + (size_t)b*CHW;
#pragma unroll
    for (int c = 0; c < CIN; ++c) {
        const unsigned short* xc = xb + (size_t)c*HWX;
        float v00 = (oky0 && okx0) ? bf2f(xc[(size_t)yc0*WW + xc0]) : 0.f;
        float v01 = (oky0 && okx1) ? bf2f(xc[(size_t)yc0*WW + xc1]) : 0.f;
        float v10 = (oky1 && okx0) ? bf2f(xc[(size_t)yc1*WW + xc0]) : 0.f;
        float v11 = (oky1 && okx1) ? bf2f(xc[(size_t)yc1*WW + xc1]) : 0.f;
        float v = v00*w00 + v01*w01 + v10*w10 + v11*w11;
        A2[(size_t)p*KDIM + c*KPTS + k] = f2bf(v);
    }
}

// ---------------------------------------------------------------------------
// GEMM2 (MFMA, depth-2 pipelined): C[p][o] = A2[p][:].dconvw[o][:] (fp32 out)
// + fused BN partial sums; grid 588 (98 row x 6 col), bijective XCD swizzle
// ---------------------------------------------------------------------------
__global__ __launch_bounds__(256) void gemm_deform(
    const unsigned short* __restrict__ A, const unsigned short* __restrict__ Bw,
    float* __restrict__ C, float* __restrict__ psum, float* __restrict__ psq)
{
    __shared__ unsigned short lds[3*8192];
    __shared__ float redS[2][128];
    __shared__ float redQ[2][128];
    const int t = threadIdx.x;
    const int lane = t & 63;
    const int w = t >> 6, wr = w >> 1, wc = w & 1;

    // bijective XCD swizzle: 588 = 4*74 + 4*73
    int bid = blockIdx.x;
    int xcd = bid & 7, j = bid >> 3;
    int idx = (xcd < 4) ? xcd*74 + j : 296 + (xcd-4)*73 + j;
    const int rblk = idx / 6;
    const int bm = rblk*128, bn = (idx % 6)*128;

    const int rq = t >> 2;
    const int ksw = (((t & 3) ^ ((t >> 3) & 3)) << 3);

    const unsigned short* aS0 = A + (size_t)(bm + rq)*KDIM + ksw;
    const unsigned short* aS1 = A + (size_t)(bm + 64 + rq)*KDIM + ksw;
    const unsigned short* bS0 = Bw + (size_t)(bn + rq)*KDIM + ksw;
    const unsigned short* bS1 = Bw + (size_t)(bn + 64 + rq)*KDIM + ksw;

    const int row_a = wr*64 + (lane & 15);
    const int row_b = wc*64 + (lane & 15);
    const int klocs = (((lane >> 4) ^ ((lane >> 1) & 3)) << 3);

#define STG2(slot, k0) do { \
        unsigned short* d = lds + (slot)*8192 + t*8; \
        GLOAD16(aS0 + (k0), d); \
        GLOAD16(aS1 + (k0), d + 2048); \
        GLOAD16(bS0 + (k0), d + 4096); \
        GLOAD16(bS1 + (k0), d + 6144); \
    } while(0)

    f32x4 acc[4][4] = {};
    STG2(0, 0); STG2(1, 32);
    asm volatile("s_waitcnt vmcnt(4)" ::: "memory");
    __builtin_amdgcn_s_barrier();
#pragma unroll
    for (int it = 0; it < 24; ++it) {
        if (it + 2 < 24) STG2((it+2)%3, (it+2)*32);
        const unsigned short* As_ = lds + (it%3)*8192;
        const unsigned short* Bs_ = As_ + 4096;
        short8 af[4], bv[4];
#pragma unroll
        for (int m = 0; m < 4; ++m) af[m] = *(const short8*)&As_[(row_a + m*16)*32 + klocs];
#pragma unroll
        for (int n = 0; n < 4; ++n) bv[n] = *(const short8*)&Bs_[(row_b + n*16)*32 + klocs];
#pragma unroll
        for (int m = 0; m < 4; ++m)
#pragma unroll
            for (int n = 0; n < 4; ++n)
                acc[m][n] = __builtin_amdgcn_mfma_f32_16x16x32_bf16(af[m], bv[n], acc[m][n], 0, 0, 0);
        if (it < 22) { asm volatile("s_waitcnt vmcnt(4) lgkmcnt(0)" ::: "memory"); __builtin_amdgcn_s_barrier(); }
        else if (it == 22) { asm volatile("s_waitcnt vmcnt(0) lgkmcnt(0)" ::: "memory"); __builtin_amdgcn_s_barrier(); }
    }
#undef STG2

    // per-thread column partial sums
    float s[4] = {}, q[4] = {};
#pragma unroll
    for (int m = 0; m < 4; ++m)
#pragma unroll
        for (int n = 0; n < 4; ++n)
#pragma unroll
            for (int r = 0; r < 4; ++r) {
                float v = acc[m][n][r];
                s[n] += v; q[n] += v*v;
            }
#pragma unroll
    for (int n = 0; n < 4; ++n) {
        s[n] += __shfl_xor(s[n], 16); q[n] += __shfl_xor(q[n], 16);
        s[n] += __shfl_xor(s[n], 32); q[n] += __shfl_xor(q[n], 32);
    }
    if (lane < 16) {
#pragma unroll
        for (int n = 0; n < 4; ++n) {
            redS[wr][wc*64 + n*16 + lane] = s[n];
            redQ[wr][wc*64 + n*16 + lane] = q[n];
        }
    }
    __syncthreads();

    // C store (fp32, d_out layout)
    const int col0 = bn + wc*64 + (lane & 15);
    const int r0 = (lane >> 4) * 4;
#pragma unroll
    for (int m = 0; m < 4; ++m) {
        int grow = bm + wr*64 + m*16 + r0;
#pragma unroll
        for (int n = 0; n < 4; ++n) {
            int gcol = col0 + n*16;
#pragma unroll
            for (int r = 0; r < 4; ++r)
                C[(size_t)(grow + r)*NOUT + gcol] = acc[m][n][r];
        }
    }
    if (t < 128) {
        psum[(size_t)rblk*NOUT + bn + t] = redS[0][t] + redS[1][t];
        psq [(size_t)rblk*NOUT + bn + t] = redQ[0][t] + redQ[1][t];
    }
}

// ---------------------------------------------------------------------------
__global__ __launch_bounds__(256) void bn_final(
    const float* __restrict__ psum, const float* __restrict__ psq,
    const float* __restrict__ gamma, const float* __restrict__ beta,
    float* __restrict__ scale, float* __restrict__ shift)
{
    int o = blockIdx.x*256 + threadIdx.x;
    float s = 0.f, q = 0.f;
    for (int i = 0; i < NRB; ++i) {
        s += psum[(size_t)i*NOUT + o];
        q += psq [(size_t)i*NOUT + o];
    }
    float mean = s * (1.0f/(float)NPATCH);
    float var  = q * (1.0f/(float)NPATCH) - mean*mean;
    float inv  = 1.0f / sqrtf(var + EPSF);
    float sc   = gamma[o] * inv;
    scale[o] = sc;
    shift[o] = beta[o] - mean*sc;
}

// ---------------------------------------------------------------------------
// In-place normalize + exact GELU on d_out
// ---------------------------------------------------------------------------
__global__ __launch_bounds__(256) void norm_gelu(
    float* __restrict__ y, const float* __restrict__ scale,
    const float* __restrict__ shift)
{
    __shared__ float ssc[NOUT], ssh[NOUT];
    for (int i = threadIdx.x; i < NOUT; i += 256) { ssc[i] = scale[i]; ssh[i] = shift[i]; }
    __syncthreads();
    const size_t total4 = (size_t)NPATCH * NOUT / 4;
    for (size_t i = (size_t)blockIdx.x*256 + threadIdx.x; i < total4;
         i += (size_t)gridDim.x*256) {
        float4 v = ((float4*)y)[i];
        int og = (int)(i % (NOUT/4));
        float4 sc = ((const float4*)ssc)[og];
        float4 sh = ((const float4*)ssh)[og];
        v.x = gelu_exact(v.x*sc.x + sh.x);
        v.y = gelu_exact(v.y*sc.y + sh.y);
        v.z = gelu_exact(v.z*sc.z + sh.z);
        v.w = gelu_exact(v.w*sc.w + sh.w);
        ((float4*)y)[i] = v;
    }
}

// ---------------------------------------------------------------------------
extern "C" void kernel_launch(void* const* d_in, const int* in_sizes, int n_in,
                              void* d_out, int out_size, void* d_ws, size_t ws_size,
                              hipStream_t stream)
{
    const float* x      = (const float*)d_in[0];
    const float* offw   = (const float*)d_in[1];
    const float* offb   = (const float*)d_in[2];
    const float* dconvw = (const float*)d_in[3];
    const float* gamma  = (const float*)d_in[4];
    const float* beta   = (const float*)d_in[5];
    float* out = (float*)d_out;

    const int NX = BATCH*CHW;           // 9,633,792
    const int NW1 = NOFF*KDIM;          // 393,216
    const int NW2 = NOUT*KDIM;          // 589,824

    unsigned short* xbf   = (unsigned short*)d_ws;
    unsigned short* wbf1  = xbf  + (size_t)NX;
    unsigned short* wbf2  = wbf1 + (size_t)NW1;
    unsigned short* A2    = wbf2 + (size_t)NW2;                 // NPATCH*KDIM
    unsigned short* off   = A2   + (size_t)NPATCH*KDIM;         // NPATCH*NOFF
    float* fscratch = (float*)(off + (size_t)NPATCH*NOFF);
    float* psum  = fscratch;            // 98*768
    float* psq   = psum + NRB*NOUT;
    float* scale = psq  + NRB*NOUT;
    float* shift = scale + NOUT;

    cvt_bf16<<<(NX/4 + 255)/256, 256, 0, stream>>>(x, xbf, NX/4);
    cvt_bf16<<<(NW1/4 + 255)/256, 256, 0, stream>>>(offw, wbf1, NW1/4);
    cvt_bf16<<<(NW2/4 + 255)/256, 256, 0, stream>>>(dconvw, wbf2, NW2/4);

    gemm_offsets<<<392, 256, 0, stream>>>(xbf, wbf1, offb, off);
    sampler<<<NPATCH, 256, 0, stream>>>(xbf, (const unsigned int*)off, A2);
    gemm_deform<<<588, 256, 0, stream>>>(A2, wbf2, out, psum, psq);
    bn_final<<<3, 256, 0, stream>>>(psum, psq, gamma, beta, scale, shift);
    norm_gelu<<<2048, 256, 0, stream>>>(out, scale, shift);
}

// Round 6
// 111.484 us; speedup vs baseline: 3.9526x; 1.0587x over previous
//
#include <hip/hip_runtime.h>
#include <math.h>

#define PATCH 16
#define BATCH 64
#define CIN 3
#define HH 224
#define WW 224
#define NPATCH (BATCH*14*14)       // 12544
#define KDIM 768                   // CIN*PATCH*PATCH
#define NOFF 512                   // 2*K
#define NOUT 768
#define KPTS 256
#define EPSF 1e-5f
#define CHW (CIN*HH*WW)            // 150528
#define HWX (HH*WW)                // 50176
#define NRB (NPATCH/128)           // 98 row blocks

using short8 = __attribute__((ext_vector_type(8))) short;
using f32x4  = __attribute__((ext_vector_type(4))) float;

#define GLOAD16(g, l) __builtin_amdgcn_global_load_lds( \
    (const __attribute__((address_space(1))) void*)(g), \
    (__attribute__((address_space(3))) void*)(l), 16, 0, 0)

__device__ __forceinline__ unsigned short f2bf(float f) {
    unsigned int u = __float_as_uint(f);
    u = (u + 0x7fffu + ((u >> 16) & 1u)) >> 16;   // RNE
    return (unsigned short)u;
}
__device__ __forceinline__ float bf2f(unsigned short h) {
    return __uint_as_float(((unsigned int)h) << 16);
}
__device__ __forceinline__ float gelu_exact(float v) {
    return 0.5f * v * (1.0f + erff(v * 0.70710678118654752440f));
}

// ---------------------------------------------------------------------------
// fused fp32 -> bf16 bulk convert for x, offw, dconvw (one launch)
// ---------------------------------------------------------------------------
#define N4X (BATCH*CHW/4)          // 2,408,448
#define N4W1 (NOFF*KDIM/4)         //    98,304
#define N4W2 (NOUT*KDIM/4)         //   147,456
#define N4ALL (N4X+N4W1+N4W2)

__global__ __launch_bounds__(256) void cvt_all(
    const float* __restrict__ x, const float* __restrict__ w1,
    const float* __restrict__ w2, unsigned short* __restrict__ xbf,
    unsigned short* __restrict__ wbf1, unsigned short* __restrict__ wbf2)
{
    for (int i = blockIdx.x*256 + threadIdx.x; i < N4ALL; i += gridDim.x*256) {
        const float* src; unsigned short* dst; int j;
        if (i < N4X)            { src = x;  dst = xbf;  j = i; }
        else if (i < N4X+N4W1)  { src = w1; dst = wbf1; j = i - N4X; }
        else                    { src = w2; dst = wbf2; j = i - N4X - N4W1; }
        float4 v = ((const float4*)src)[j];
        ((ushort4*)dst)[j] = make_ushort4(f2bf(v.x), f2bf(v.y), f2bf(v.z), f2bf(v.w));
    }
}

// ---------------------------------------------------------------------------
// GEMM1 (MFMA, depth-2 pipelined): off[p][n] = patch(xbf)[p][:].offw[n][:]+b
// grid: 392 blocks (98 row x 4 col), XCD-swizzled (392%8==0)
// LDS swizzle: chunk ^= row bits[2:1] (2-bit XOR involution)
// lgkmcnt(0) drained before every raw s_barrier (3-slot reuse distance 1).
// ---------------------------------------------------------------------------
__global__ __launch_bounds__(256) void gemm_offsets(
    const unsigned short* __restrict__ xbf, const unsigned short* __restrict__ Bw,
    const float* __restrict__ offb, unsigned short* __restrict__ off)
{
    __shared__ unsigned short lds[3*8192];
    const int t = threadIdx.x;
    const int lane = t & 63;
    const int w = t >> 6, wr = w >> 1, wc = w & 1;

    // XCD swizzle: 392 = 8*49
    int bid = blockIdx.x;
    int idx = (bid & 7)*49 + (bid >> 3);
    const int bm = (idx >> 2) * 128, bn = (idx & 3) * 128;

    const int rq = t >> 2;
    const int ksw = (((t & 3) ^ ((t >> 3) & 3)) << 3);   // swizzled k-chunk (shorts)

    const unsigned short* aBase0;
    const unsigned short* aBase1;
    {
        int p0 = bm + rq,      b0 = p0/196, r0 = p0%196;
        int p1 = bm + 64 + rq, b1 = p1/196, r1 = p1%196;
        aBase0 = xbf + (size_t)b0*CHW + (size_t)((r0/14)*PATCH)*WW + (size_t)((r0%14)*PATCH);
        aBase1 = xbf + (size_t)b1*CHW + (size_t)((r1/14)*PATCH)*WW + (size_t)((r1%14)*PATCH);
    }
    const unsigned short* bS0 = Bw + (size_t)(bn + rq)*KDIM + ksw;
    const unsigned short* bS1 = Bw + (size_t)(bn + 64 + rq)*KDIM + ksw;

    const int row_a = wr*64 + (lane & 15);
    const int row_b = wc*64 + (lane & 15);
    const int klocs = (((lane >> 4) ^ ((lane >> 1) & 3)) << 3);

#define STG1(slot, k0) do { \
        unsigned short* d = lds + (slot)*8192 + t*8; \
        int e = (k0) + ksw; \
        size_t xo = (size_t)(e >> 8)*HWX + (size_t)((e >> 4) & 15)*WW + (e & 15); \
        GLOAD16(aBase0 + xo, d); \
        GLOAD16(aBase1 + xo, d + 2048); \
        GLOAD16(bS0 + (k0), d + 4096); \
        GLOAD16(bS1 + (k0), d + 6144); \
    } while(0)

    f32x4 acc[4][4] = {};
    STG1(0, 0); STG1(1, 32);
    asm volatile("s_waitcnt vmcnt(4)" ::: "memory");
    __builtin_amdgcn_s_barrier();
#pragma unroll
    for (int it = 0; it < 24; ++it) {
        if (it + 2 < 24) STG1((it+2)%3, (it+2)*32);
        const unsigned short* As_ = lds + (it%3)*8192;
        const unsigned short* Bs_ = As_ + 4096;
        short8 af[4], bv[4];
#pragma unroll
        for (int m = 0; m < 4; ++m) af[m] = *(const short8*)&As_[(row_a + m*16)*32 + klocs];
#pragma unroll
        for (int n = 0; n < 4; ++n) bv[n] = *(const short8*)&Bs_[(row_b + n*16)*32 + klocs];
        __builtin_amdgcn_s_setprio(1);
#pragma unroll
        for (int m = 0; m < 4; ++m)
#pragma unroll
            for (int n = 0; n < 4; ++n)
                acc[m][n] = __builtin_amdgcn_mfma_f32_16x16x32_bf16(af[m], bv[n], acc[m][n], 0, 0, 0);
        __builtin_amdgcn_s_setprio(0);
        if (it < 22) { asm volatile("s_waitcnt vmcnt(4) lgkmcnt(0)" ::: "memory"); __builtin_amdgcn_s_barrier(); }
        else if (it == 22) { asm volatile("s_waitcnt vmcnt(0) lgkmcnt(0)" ::: "memory"); __builtin_amdgcn_s_barrier(); }
    }
#undef STG1

    const int col0 = bn + wc*64 + (lane & 15);
    const int r0 = (lane >> 4) * 4;
#pragma unroll
    for (int m = 0; m < 4; ++m) {
        int grow = bm + wr*64 + m*16 + r0;
#pragma unroll
        for (int n = 0; n < 4; ++n) {
            int gcol = col0 + n*16;
            float bias = offb[gcol];
#pragma unroll
            for (int r = 0; r < 4; ++r)
                off[(size_t)(grow + r)*NOFF + gcol] = f2bf(acc[m][n][r] + bias);
        }
    }
}

// ---------------------------------------------------------------------------
// Sampler: A2bf[p][c*256+k] = bilinear(xbf[b][c], py, px), zero-pad OOB
// ---------------------------------------------------------------------------
__global__ __launch_bounds__(256) void sampler(
    const unsigned short* __restrict__ xbf, const unsigned int* __restrict__ offu,
    unsigned short* __restrict__ A2)
{
    int p = blockIdx.x;
    int k = threadIdx.x;
    int b = p / 196, rem = p % 196;
    int ho = rem / 14, wo = rem % 14;

    unsigned int d2 = offu[(size_t)p*KPTS + k];          // lo=dy, hi=dx (bf16)
    float dy = __uint_as_float((d2 & 0xffffu) << 16);
    float dx = __uint_as_float(d2 & 0xffff0000u);
    float py = (float)(ho*PATCH + (k >> 4)) + dy;
    float px = (float)(wo*PATCH + (k & 15)) + dx;
    float fy = floorf(py), fx = floorf(px);
    float wy1 = py - fy, wx1 = px - fx;
    float wy0 = 1.f - wy1, wx0 = 1.f - wx1;
    int y0 = (int)fy, x0 = (int)fx;
    int y1 = y0 + 1, x1 = x0 + 1;
    bool oky0 = (y0 >= 0) & (y0 < HH);
    bool oky1 = (y1 >= 0) & (y1 < HH);
    bool okx0 = (x0 >= 0) & (x0 < WW);
    bool okx1 = (x1 >= 0) & (x1 < WW);
    int yc0 = min(max(y0, 0), HH-1), yc1 = min(max(y1, 0), HH-1);
    int xc0 = min(max(x0, 0), WW-1), xc1 = min(max(x1, 0), WW-1);
    float w00 = wy0*wx0, w01 = wy0*wx1, w10 = wy1*wx0, w11 = wy1*wx1;

    const unsigned short* xb = xbf + (size_t)b*CHW;
#pragma unroll
    for (int c = 0; c < CIN; ++c) {
        const unsigned short* xc = xb + (size_t)c*HWX;
        float v00 = (oky0 && okx0) ? bf2f(xc[(size_t)yc0*WW + xc0]) : 0.f;
        float v01 = (oky0 && okx1) ? bf2f(xc[(size_t)yc0*WW + xc1]) : 0.f;
        float v10 = (oky1 && okx0) ? bf2f(xc[(size_t)yc1*WW + xc0]) : 0.f;
        float v11 = (oky1 && okx1) ? bf2f(xc[(size_t)yc1*WW + xc1]) : 0.f;
        float v = v00*w00 + v01*w01 + v10*w10 + v11*w11;
        A2[(size_t)p*KDIM + c*KPTS + k] = f2bf(v);
    }
}

// ---------------------------------------------------------------------------
// GEMM2 (MFMA, depth-2 pipelined): ybf[p][o] = A2[p][:].dconvw[o][:] (bf16)
// + fused BN partial sums (from fp32 acc); grid 588, bijective XCD swizzle
// ---------------------------------------------------------------------------
__global__ __launch_bounds__(256) void gemm_deform(
    const unsigned short* __restrict__ A, const unsigned short* __restrict__ Bw,
    unsigned short* __restrict__ Cbf, float* __restrict__ psum, float* __restrict__ psq)
{
    __shared__ unsigned short lds[3*8192];
    __shared__ float redS[2][128];
    __shared__ float redQ[2][128];
    const int t = threadIdx.x;
    const int lane = t & 63;
    const int w = t >> 6, wr = w >> 1, wc = w & 1;

    // bijective XCD swizzle: 588 = 4*74 + 4*73
    int bid = blockIdx.x;
    int xcd = bid & 7, j = bid >> 3;
    int idx = (xcd < 4) ? xcd*74 + j : 296 + (xcd-4)*73 + j;
    const int rblk = idx / 6;
    const int bm = rblk*128, bn = (idx % 6)*128;

    const int rq = t >> 2;
    const int ksw = (((t & 3) ^ ((t >> 3) & 3)) << 3);

    const unsigned short* aS0 = A + (size_t)(bm + rq)*KDIM + ksw;
    const unsigned short* aS1 = A + (size_t)(bm + 64 + rq)*KDIM + ksw;
    const unsigned short* bS0 = Bw + (size_t)(bn + rq)*KDIM + ksw;
    const unsigned short* bS1 = Bw + (size_t)(bn + 64 + rq)*KDIM + ksw;

    const int row_a = wr*64 + (lane & 15);
    const int row_b = wc*64 + (lane & 15);
    const int klocs = (((lane >> 4) ^ ((lane >> 1) & 3)) << 3);

#define STG2(slot, k0) do { \
        unsigned short* d = lds + (slot)*8192 + t*8; \
        GLOAD16(aS0 + (k0), d); \
        GLOAD16(aS1 + (k0), d + 2048); \
        GLOAD16(bS0 + (k0), d + 4096); \
        GLOAD16(bS1 + (k0), d + 6144); \
    } while(0)

    f32x4 acc[4][4] = {};
    STG2(0, 0); STG2(1, 32);
    asm volatile("s_waitcnt vmcnt(4)" ::: "memory");
    __builtin_amdgcn_s_barrier();
#pragma unroll
    for (int it = 0; it < 24; ++it) {
        if (it + 2 < 24) STG2((it+2)%3, (it+2)*32);
        const unsigned short* As_ = lds + (it%3)*8192;
        const unsigned short* Bs_ = As_ + 4096;
        short8 af[4], bv[4];
#pragma unroll
        for (int m = 0; m < 4; ++m) af[m] = *(const short8*)&As_[(row_a + m*16)*32 + klocs];
#pragma unroll
        for (int n = 0; n < 4; ++n) bv[n] = *(const short8*)&Bs_[(row_b + n*16)*32 + klocs];
        __builtin_amdgcn_s_setprio(1);
#pragma unroll
        for (int m = 0; m < 4; ++m)
#pragma unroll
            for (int n = 0; n < 4; ++n)
                acc[m][n] = __builtin_amdgcn_mfma_f32_16x16x32_bf16(af[m], bv[n], acc[m][n], 0, 0, 0);
        __builtin_amdgcn_s_setprio(0);
        if (it < 22) { asm volatile("s_waitcnt vmcnt(4) lgkmcnt(0)" ::: "memory"); __builtin_amdgcn_s_barrier(); }
        else if (it == 22) { asm volatile("s_waitcnt vmcnt(0) lgkmcnt(0)" ::: "memory"); __builtin_amdgcn_s_barrier(); }
    }
#undef STG2

    // per-thread column partial sums (fp32, from accumulators)
    float s[4] = {}, q[4] = {};
#pragma unroll
    for (int m = 0; m < 4; ++m)
#pragma unroll
        for (int n = 0; n < 4; ++n)
#pragma unroll
            for (int r = 0; r < 4; ++r) {
                float v = acc[m][n][r];
                s[n] += v; q[n] += v*v;
            }
#pragma unroll
    for (int n = 0; n < 4; ++n) {
        s[n] += __shfl_xor(s[n], 16); q[n] += __shfl_xor(q[n], 16);
        s[n] += __shfl_xor(s[n], 32); q[n] += __shfl_xor(q[n], 32);
    }
    if (lane < 16) {
#pragma unroll
        for (int n = 0; n < 4; ++n) {
            redS[wr][wc*64 + n*16 + lane] = s[n];
            redQ[wr][wc*64 + n*16 + lane] = q[n];
        }
    }
    __syncthreads();

    // y store (bf16, d_out row layout)
    const int col0 = bn + wc*64 + (lane & 15);
    const int r0 = (lane >> 4) * 4;
#pragma unroll
    for (int m = 0; m < 4; ++m) {
        int grow = bm + wr*64 + m*16 + r0;
#pragma unroll
        for (int n = 0; n < 4; ++n) {
            int gcol = col0 + n*16;
#pragma unroll
            for (int r = 0; r < 4; ++r)
                Cbf[(size_t)(grow + r)*NOUT + gcol] = f2bf(acc[m][n][r]);
        }
    }
    if (t < 128) {
        psum[(size_t)rblk*NOUT + bn + t] = redS[0][t] + redS[1][t];
        psq [(size_t)rblk*NOUT + bn + t] = redQ[0][t] + redQ[1][t];
    }
}

// ---------------------------------------------------------------------------
__global__ __launch_bounds__(256) void bn_final(
    const float* __restrict__ psum, const float* __restrict__ psq,
    const float* __restrict__ gamma, const float* __restrict__ beta,
    float* __restrict__ scale, float* __restrict__ shift)
{
    int o = blockIdx.x*256 + threadIdx.x;
    float s = 0.f, q = 0.f;
    for (int i = 0; i < NRB; ++i) {
        s += psum[(size_t)i*NOUT + o];
        q += psq [(size_t)i*NOUT + o];
    }
    float mean = s * (1.0f/(float)NPATCH);
    float var  = q * (1.0f/(float)NPATCH) - mean*mean;
    float inv  = 1.0f / sqrtf(var + EPSF);
    float sc   = gamma[o] * inv;
    scale[o] = sc;
    shift[o] = beta[o] - mean*sc;
}

// ---------------------------------------------------------------------------
// normalize + exact GELU: read bf16 y (ws), write fp32 d_out
// ---------------------------------------------------------------------------
__global__ __launch_bounds__(256) void norm_gelu(
    const unsigned short* __restrict__ ybf, float* __restrict__ out,
    const float* __restrict__ scale, const float* __restrict__ shift)
{
    __shared__ float ssc[NOUT], ssh[NOUT];
    for (int i = threadIdx.x; i < NOUT; i += 256) { ssc[i] = scale[i]; ssh[i] = shift[i]; }
    __syncthreads();
    const size_t total8 = (size_t)NPATCH * NOUT / 8;
    for (size_t i = (size_t)blockIdx.x*256 + threadIdx.x; i < total8;
         i += (size_t)gridDim.x*256) {
        uint4 v = ((const uint4*)ybf)[i];                 // 8 bf16
        int og = (int)(i % (NOUT/8)) * 8;
        float4 o0, o1;
        o0.x = gelu_exact(__uint_as_float(v.x << 16)        * ssc[og+0] + ssh[og+0]);
        o0.y = gelu_exact(__uint_as_float(v.x & 0xffff0000u)* ssc[og+1] + ssh[og+1]);
        o0.z = gelu_exact(__uint_as_float(v.y << 16)        * ssc[og+2] + ssh[og+2]);
        o0.w = gelu_exact(__uint_as_float(v.y & 0xffff0000u)* ssc[og+3] + ssh[og+3]);
        o1.x = gelu_exact(__uint_as_float(v.z << 16)        * ssc[og+4] + ssh[og+4]);
        o1.y = gelu_exact(__uint_as_float(v.z & 0xffff0000u)* ssc[og+5] + ssh[og+5]);
        o1.z = gelu_exact(__uint_as_float(v.w << 16)        * ssc[og+6] + ssh[og+6]);
        o1.w = gelu_exact(__uint_as_float(v.w & 0xffff0000u)* ssc[og+7] + ssh[og+7]);
        ((float4*)out)[2*i]   = o0;
        ((float4*)out)[2*i+1] = o1;
    }
}

// ---------------------------------------------------------------------------
extern "C" void kernel_launch(void* const* d_in, const int* in_sizes, int n_in,
                              void* d_out, int out_size, void* d_ws, size_t ws_size,
                              hipStream_t stream)
{
    const float* x      = (const float*)d_in[0];
    const float* offw   = (const float*)d_in[1];
    const float* offb   = (const float*)d_in[2];
    const float* dconvw = (const float*)d_in[3];
    const float* gamma  = (const float*)d_in[4];
    const float* beta   = (const float*)d_in[5];
    float* out = (float*)d_out;

    const size_t NX  = (size_t)BATCH*CHW;   // 9,633,792
    const size_t NW1 = (size_t)NOFF*KDIM;   // 393,216
    const size_t NW2 = (size_t)NOUT*KDIM;   // 589,824

    unsigned short* xbf   = (unsigned short*)d_ws;
    unsigned short* wbf1  = xbf  + NX;
    unsigned short* wbf2  = wbf1 + NW1;
    unsigned short* A2    = wbf2 + NW2;                       // NPATCH*KDIM
    unsigned short* off   = A2   + (size_t)NPATCH*KDIM;       // NPATCH*NOFF
    unsigned short* ybf   = off  + (size_t)NPATCH*NOFF;       // NPATCH*NOUT
    float* fscratch = (float*)(ybf + (size_t)NPATCH*NOUT);
    float* psum  = fscratch;            // 98*768
    float* psq   = psum + NRB*NOUT;
    float* scale = psq  + NRB*NOUT;
    float* shift = scale + NOUT;

    cvt_all<<<4096, 256, 0, stream>>>(x, offw, dconvw, xbf, wbf1, wbf2);
    gemm_offsets<<<392, 256, 0, stream>>>(xbf, wbf1, offb, off);
    sampler<<<NPATCH, 256, 0, stream>>>(xbf, (const unsigned int*)off, A2);
    gemm_deform<<<588, 256, 0, stream>>>(A2, wbf2, ybf, psum, psq);
    bn_final<<<3, 256, 0, stream>>>(psum, psq, gamma, beta, scale, shift);
    norm_gelu<<<2048, 256, 0, stream>>>(ybf, out, scale, shift);
}

// Round 7
// 103.622 us; speedup vs baseline: 4.2525x; 1.0759x over previous
//
#include <hip/hip_runtime.h>
#include <math.h>

#define PATCH 16
#define BATCH 64
#define CIN 3
#define HH 224
#define WW 224
#define NPATCH (BATCH*14*14)       // 12544
#define KDIM 768                   // CIN*PATCH*PATCH
#define NOFF 512                   // 2*K
#define NOUT 768
#define KPTS 256
#define EPSF 1e-5f
#define CHW (CIN*HH*WW)            // 150528
#define HWX (HH*WW)                // 50176
#define NRB (NPATCH/128)           // 98 row blocks

using short8 = __attribute__((ext_vector_type(8))) short;
using f32x4  = __attribute__((ext_vector_type(4))) float;

#define GLOAD16(g, l) __builtin_amdgcn_global_load_lds( \
    (const __attribute__((address_space(1))) void*)(g), \
    (__attribute__((address_space(3))) void*)(l), 16, 0, 0)

__device__ __forceinline__ unsigned short f2bf(float f) {
    unsigned int u = __float_as_uint(f);
    u = (u + 0x7fffu + ((u >> 16) & 1u)) >> 16;   // RNE
    return (unsigned short)u;
}
__device__ __forceinline__ float bf2f(unsigned short h) {
    return __uint_as_float(((unsigned int)h) << 16);
}
__device__ __forceinline__ float gelu_exact(float v) {
    return 0.5f * v * (1.0f + erff(v * 0.70710678118654752440f));
}

// ---------------------------------------------------------------------------
// fused fp32 -> bf16 bulk convert for x, offw, dconvw (one launch)
// ---------------------------------------------------------------------------
#define N4X (BATCH*CHW/4)          // 2,408,448
#define N4W1 (NOFF*KDIM/4)         //    98,304
#define N4W2 (NOUT*KDIM/4)         //   147,456
#define N4ALL (N4X+N4W1+N4W2)

__global__ __launch_bounds__(256) void cvt_all(
    const float* __restrict__ x, const float* __restrict__ w1,
    const float* __restrict__ w2, unsigned short* __restrict__ xbf,
    unsigned short* __restrict__ wbf1, unsigned short* __restrict__ wbf2)
{
    for (int i = blockIdx.x*256 + threadIdx.x; i < N4ALL; i += gridDim.x*256) {
        const float* src; unsigned short* dst; int j;
        if (i < N4X)            { src = x;  dst = xbf;  j = i; }
        else if (i < N4X+N4W1)  { src = w1; dst = wbf1; j = i - N4X; }
        else                    { src = w2; dst = wbf2; j = i - N4X - N4W1; }
        float4 v = ((const float4*)src)[j];
        ((ushort4*)dst)[j] = make_ushort4(f2bf(v.x), f2bf(v.y), f2bf(v.z), f2bf(v.w));
    }
}

// ---------------------------------------------------------------------------
// GEMM1 (MFMA, depth-3 pipelined, 4 LDS slots): off = patch(xbf).offw^T + b
// grid: 392 blocks (98 row x 4 col), XCD-swizzled
// LDS swizzle: k-chunk ^= row bits[2:1] on global SOURCE, linear dest (r#21)
// lgkmcnt(0) drained before each raw s_barrier; vmcnt 8/4/0 ladder.
// ---------------------------------------------------------------------------
__global__ __launch_bounds__(256) void gemm_offsets(
    const unsigned short* __restrict__ xbf, const unsigned short* __restrict__ Bw,
    const float* __restrict__ offb, unsigned short* __restrict__ off)
{
    __shared__ unsigned short lds[4*8192];
    const int t = threadIdx.x;
    const int lane = t & 63;
    const int w = t >> 6, wr = w >> 1, wc = w & 1;

    // XCD swizzle: 392 = 8*49
    int bid = blockIdx.x;
    int idx = (bid & 7)*49 + (bid >> 3);
    const int bm = (idx >> 2) * 128, bn = (idx & 3) * 128;

    const int rq = t >> 2;
    const int ksw = (((t & 3) ^ ((t >> 3) & 3)) << 3);   // swizzled k-chunk (shorts)

    const unsigned short* aBase0;
    const unsigned short* aBase1;
    {
        int p0 = bm + rq,      b0 = p0/196, r0 = p0%196;
        int p1 = bm + 64 + rq, b1 = p1/196, r1 = p1%196;
        aBase0 = xbf + (size_t)b0*CHW + (size_t)((r0/14)*PATCH)*WW + (size_t)((r0%14)*PATCH);
        aBase1 = xbf + (size_t)b1*CHW + (size_t)((r1/14)*PATCH)*WW + (size_t)((r1%14)*PATCH);
    }
    const unsigned short* bS0 = Bw + (size_t)(bn + rq)*KDIM + ksw;
    const unsigned short* bS1 = Bw + (size_t)(bn + 64 + rq)*KDIM + ksw;

    const int row_a = wr*64 + (lane & 15);
    const int row_b = wc*64 + (lane & 15);
    const int klocs = (((lane >> 4) ^ ((lane >> 1) & 3)) << 3);

#define STG1(slot, k0) do { \
        unsigned short* d = lds + (slot)*8192 + t*8; \
        int e = (k0) + ksw; \
        size_t xo = (size_t)(e >> 8)*HWX + (size_t)((e >> 4) & 15)*WW + (e & 15); \
        GLOAD16(aBase0 + xo, d); \
        GLOAD16(aBase1 + xo, d + 2048); \
        GLOAD16(bS0 + (k0), d + 4096); \
        GLOAD16(bS1 + (k0), d + 6144); \
    } while(0)

    f32x4 acc[4][4] = {};
    STG1(0, 0); STG1(1, 32); STG1(2, 64);
    asm volatile("s_waitcnt vmcnt(8)" ::: "memory");
    __builtin_amdgcn_s_barrier();
#pragma unroll
    for (int it = 0; it < 24; ++it) {
        if (it + 3 < 24) STG1((it+3)&3, (it+3)*32);
        const unsigned short* As_ = lds + (it&3)*8192;
        const unsigned short* Bs_ = As_ + 4096;
        short8 af[4], bv[4];
#pragma unroll
        for (int m = 0; m < 4; ++m) af[m] = *(const short8*)&As_[(row_a + m*16)*32 + klocs];
#pragma unroll
        for (int n = 0; n < 4; ++n) bv[n] = *(const short8*)&Bs_[(row_b + n*16)*32 + klocs];
        __builtin_amdgcn_s_setprio(1);
#pragma unroll
        for (int m = 0; m < 4; ++m)
#pragma unroll
            for (int n = 0; n < 4; ++n)
                acc[m][n] = __builtin_amdgcn_mfma_f32_16x16x32_bf16(af[m], bv[n], acc[m][n], 0, 0, 0);
        __builtin_amdgcn_s_setprio(0);
        if (it <= 20)      { asm volatile("s_waitcnt vmcnt(8) lgkmcnt(0)" ::: "memory"); __builtin_amdgcn_s_barrier(); }
        else if (it == 21) { asm volatile("s_waitcnt vmcnt(4) lgkmcnt(0)" ::: "memory"); __builtin_amdgcn_s_barrier(); }
        else if (it == 22) { asm volatile("s_waitcnt vmcnt(0) lgkmcnt(0)" ::: "memory"); __builtin_amdgcn_s_barrier(); }
    }
#undef STG1

    const int col0 = bn + wc*64 + (lane & 15);
    const int r0 = (lane >> 4) * 4;
#pragma unroll
    for (int m = 0; m < 4; ++m) {
        int grow = bm + wr*64 + m*16 + r0;
#pragma unroll
        for (int n = 0; n < 4; ++n) {
            int gcol = col0 + n*16;
            float bias = offb[gcol];
#pragma unroll
            for (int r = 0; r < 4; ++r)
                off[(size_t)(grow + r)*NOFF + gcol] = f2bf(acc[m][n][r] + bias);
        }
    }
}

// ---------------------------------------------------------------------------
// Sampler: LDS-staged 22x22 window per patch (+/-2 px halo), vectorized
// interior staging; clamped+ok-mask semantics identical to global path;
// per-lane global fallback for |offset| >= 2 px (rare; exact).
// ---------------------------------------------------------------------------
__global__ __launch_bounds__(256) void sampler(
    const unsigned short* __restrict__ xbf, const unsigned int* __restrict__ offu,
    unsigned short* __restrict__ A2)
{
    __shared__ unsigned short win[3][22][24];
    int p = blockIdx.x;
    int k = threadIdx.x;
    int b = p / 196, rem = p % 196;
    int ho = rem / 14, wo = rem % 14;
    const int gy0 = ho*PATCH - 2, gx0 = wo*PATCH - 2;
    const unsigned short* xb = xbf + (size_t)b*CHW;

    bool interior = (ho >= 1) && (ho <= 12) && (wo >= 1) && (wo <= 12);
    if (interior) {
        // 3ch x 22 rows x 11 dwords (22 bf16 cols), gx0 even -> 4B aligned
        for (int idx = k; idx < 3*22*11; idx += 256) {
            int c = idx / 242, r2 = idx - c*242;
            int row = r2 / 11, u = r2 - row*11;
            const unsigned int* src = (const unsigned int*)
                (xb + (size_t)c*HWX + (size_t)(gy0+row)*WW + gx0);
            *(unsigned int*)&win[c][row][2*u] = src[u];
        }
    } else {
        for (int idx = k; idx < 3*22*22; idx += 256) {
            int c = idx / 484, r2 = idx - c*484;
            int row = r2 / 22, col = r2 - row*22;
            int gy = min(max(gy0+row, 0), HH-1);
            int gx = min(max(gx0+col, 0), WW-1);
            win[c][row][col] = xb[(size_t)c*HWX + (size_t)gy*WW + gx];
        }
    }
    __syncthreads();

    unsigned int d2 = offu[(size_t)p*KPTS + k];          // lo=dy, hi=dx (bf16)
    float dy = __uint_as_float((d2 & 0xffffu) << 16);
    float dx = __uint_as_float(d2 & 0xffff0000u);
    float py = (float)(ho*PATCH + (k >> 4)) + dy;
    float px = (float)(wo*PATCH + (k & 15)) + dx;
    float fy = floorf(py), fx = floorf(px);
    float wy1 = py - fy, wx1 = px - fx;
    float wy0 = 1.f - wy1, wx0 = 1.f - wx1;
    int y0 = (int)fy, x0 = (int)fx;
    int y1 = y0 + 1, x1 = x0 + 1;
    bool oky0 = (y0 >= 0) & (y0 < HH);
    bool oky1 = (y1 >= 0) & (y1 < HH);
    bool okx0 = (x0 >= 0) & (x0 < WW);
    bool okx1 = (x1 >= 0) & (x1 < WW);
    float w00 = wy0*wx0, w01 = wy0*wx1, w10 = wy1*wx0, w11 = wy1*wx1;

    int ry = y0 - gy0, rx = x0 - gx0;
    if (ry >= 0 && ry <= 20 && rx >= 0 && rx <= 20) {
        float m00 = oky0 && okx0 ? 1.f : 0.f;
        float m01 = oky0 && okx1 ? 1.f : 0.f;
        float m10 = oky1 && okx0 ? 1.f : 0.f;
        float m11 = oky1 && okx1 ? 1.f : 0.f;
#pragma unroll
        for (int c = 0; c < CIN; ++c) {
            float v00 = bf2f(win[c][ry  ][rx  ]) * m00;
            float v01 = bf2f(win[c][ry  ][rx+1]) * m01;
            float v10 = bf2f(win[c][ry+1][rx  ]) * m10;
            float v11 = bf2f(win[c][ry+1][rx+1]) * m11;
            float v = v00*w00 + v01*w01 + v10*w10 + v11*w11;
            A2[(size_t)p*KDIM + c*KPTS + k] = f2bf(v);
        }
    } else {
        // exact global fallback (offsets beyond halo)
        int yc0 = min(max(y0, 0), HH-1), yc1 = min(max(y1, 0), HH-1);
        int xc0 = min(max(x0, 0), WW-1), xc1 = min(max(x1, 0), WW-1);
#pragma unroll
        for (int c = 0; c < CIN; ++c) {
            const unsigned short* xc = xb + (size_t)c*HWX;
            float v00 = (oky0 && okx0) ? bf2f(xc[(size_t)yc0*WW + xc0]) : 0.f;
            float v01 = (oky0 && okx1) ? bf2f(xc[(size_t)yc0*WW + xc1]) : 0.f;
            float v10 = (oky1 && okx0) ? bf2f(xc[(size_t)yc1*WW + xc0]) : 0.f;
            float v11 = (oky1 && okx1) ? bf2f(xc[(size_t)yc1*WW + xc1]) : 0.f;
            float v = v00*w00 + v01*w01 + v10*w10 + v11*w11;
            A2[(size_t)p*KDIM + c*KPTS + k] = f2bf(v);
        }
    }
}

// ---------------------------------------------------------------------------
// GEMM2 (MFMA, depth-3 pipelined, 4 LDS slots): ybf = A2 . dconvw^T (bf16)
// + fused BN partial sums; grid 588, bijective XCD swizzle
// ---------------------------------------------------------------------------
__global__ __launch_bounds__(256) void gemm_deform(
    const unsigned short* __restrict__ A, const unsigned short* __restrict__ Bw,
    unsigned short* __restrict__ Cbf, float* __restrict__ psum, float* __restrict__ psq)
{
    __shared__ unsigned short lds[4*8192];
    __shared__ float redS[2][128];
    __shared__ float redQ[2][128];
    const int t = threadIdx.x;
    const int lane = t & 63;
    const int w = t >> 6, wr = w >> 1, wc = w & 1;

    // bijective XCD swizzle: 588 = 4*74 + 4*73
    int bid = blockIdx.x;
    int xcd = bid & 7, j = bid >> 3;
    int idx = (xcd < 4) ? xcd*74 + j : 296 + (xcd-4)*73 + j;
    const int rblk = idx / 6;
    const int bm = rblk*128, bn = (idx % 6)*128;

    const int rq = t >> 2;
    const int ksw = (((t & 3) ^ ((t >> 3) & 3)) << 3);

    const unsigned short* aS0 = A + (size_t)(bm + rq)*KDIM + ksw;
    const unsigned short* aS1 = A + (size_t)(bm + 64 + rq)*KDIM + ksw;
    const unsigned short* bS0 = Bw + (size_t)(bn + rq)*KDIM + ksw;
    const unsigned short* bS1 = Bw + (size_t)(bn + 64 + rq)*KDIM + ksw;

    const int row_a = wr*64 + (lane & 15);
    const int row_b = wc*64 + (lane & 15);
    const int klocs = (((lane >> 4) ^ ((lane >> 1) & 3)) << 3);

#define STG2(slot, k0) do { \
        unsigned short* d = lds + (slot)*8192 + t*8; \
        GLOAD16(aS0 + (k0), d); \
        GLOAD16(aS1 + (k0), d + 2048); \
        GLOAD16(bS0 + (k0), d + 4096); \
        GLOAD16(bS1 + (k0), d + 6144); \
    } while(0)

    f32x4 acc[4][4] = {};
    STG2(0, 0); STG2(1, 32); STG2(2, 64);
    asm volatile("s_waitcnt vmcnt(8)" ::: "memory");
    __builtin_amdgcn_s_barrier();
#pragma unroll
    for (int it = 0; it < 24; ++it) {
        if (it + 3 < 24) STG2((it+3)&3, (it+3)*32);
        const unsigned short* As_ = lds + (it&3)*8192;
        const unsigned short* Bs_ = As_ + 4096;
        short8 af[4], bv[4];
#pragma unroll
        for (int m = 0; m < 4; ++m) af[m] = *(const short8*)&As_[(row_a + m*16)*32 + klocs];
#pragma unroll
        for (int n = 0; n < 4; ++n) bv[n] = *(const short8*)&Bs_[(row_b + n*16)*32 + klocs];
        __builtin_amdgcn_s_setprio(1);
#pragma unroll
        for (int m = 0; m < 4; ++m)
#pragma unroll
            for (int n = 0; n < 4; ++n)
                acc[m][n] = __builtin_amdgcn_mfma_f32_16x16x32_bf16(af[m], bv[n], acc[m][n], 0, 0, 0);
        __builtin_amdgcn_s_setprio(0);
        if (it <= 20)      { asm volatile("s_waitcnt vmcnt(8) lgkmcnt(0)" ::: "memory"); __builtin_amdgcn_s_barrier(); }
        else if (it == 21) { asm volatile("s_waitcnt vmcnt(4) lgkmcnt(0)" ::: "memory"); __builtin_amdgcn_s_barrier(); }
        else if (it == 22) { asm volatile("s_waitcnt vmcnt(0) lgkmcnt(0)" ::: "memory"); __builtin_amdgcn_s_barrier(); }
    }
#undef STG2

    // per-thread column partial sums (fp32, from accumulators)
    float s[4] = {}, q[4] = {};
#pragma unroll
    for (int m = 0; m < 4; ++m)
#pragma unroll
        for (int n = 0; n < 4; ++n)
#pragma unroll
            for (int r = 0; r < 4; ++r) {
                float v = acc[m][n][r];
                s[n] += v; q[n] += v*v;
            }
#pragma unroll
    for (int n = 0; n < 4; ++n) {
        s[n] += __shfl_xor(s[n], 16); q[n] += __shfl_xor(q[n], 16);
        s[n] += __shfl_xor(s[n], 32); q[n] += __shfl_xor(q[n], 32);
    }
    if (lane < 16) {
#pragma unroll
        for (int n = 0; n < 4; ++n) {
            redS[wr][wc*64 + n*16 + lane] = s[n];
            redQ[wr][wc*64 + n*16 + lane] = q[n];
        }
    }
    __syncthreads();

    // y store (bf16, d_out row layout)
    const int col0 = bn + wc*64 + (lane & 15);
    const int r0 = (lane >> 4) * 4;
#pragma unroll
    for (int m = 0; m < 4; ++m) {
        int grow = bm + wr*64 + m*16 + r0;
#pragma unroll
        for (int n = 0; n < 4; ++n) {
            int gcol = col0 + n*16;
#pragma unroll
            for (int r = 0; r < 4; ++r)
                Cbf[(size_t)(grow + r)*NOUT + gcol] = f2bf(acc[m][n][r]);
        }
    }
    if (t < 128) {
        psum[(size_t)rblk*NOUT + bn + t] = redS[0][t] + redS[1][t];
        psq [(size_t)rblk*NOUT + bn + t] = redQ[0][t] + redQ[1][t];
    }
}

// ---------------------------------------------------------------------------
__global__ __launch_bounds__(256) void bn_final(
    const float* __restrict__ psum, const float* __restrict__ psq,
    const float* __restrict__ gamma, const float* __restrict__ beta,
    float* __restrict__ scale, float* __restrict__ shift)
{
    int o = blockIdx.x*256 + threadIdx.x;
    float s = 0.f, q = 0.f;
    for (int i = 0; i < NRB; ++i) {
        s += psum[(size_t)i*NOUT + o];
        q += psq [(size_t)i*NOUT + o];
    }
    float mean = s * (1.0f/(float)NPATCH);
    float var  = q * (1.0f/(float)NPATCH) - mean*mean;
    float inv  = 1.0f / sqrtf(var + EPSF);
    float sc   = gamma[o] * inv;
    scale[o] = sc;
    shift[o] = beta[o] - mean*sc;
}

// ---------------------------------------------------------------------------
// normalize + exact GELU: read bf16 y (ws), write fp32 d_out
// ---------------------------------------------------------------------------
__global__ __launch_bounds__(256) void norm_gelu(
    const unsigned short* __restrict__ ybf, float* __restrict__ out,
    const float* __restrict__ scale, const float* __restrict__ shift)
{
    __shared__ float ssc[NOUT], ssh[NOUT];
    for (int i = threadIdx.x; i < NOUT; i += 256) { ssc[i] = scale[i]; ssh[i] = shift[i]; }
    __syncthreads();
    const size_t total8 = (size_t)NPATCH * NOUT / 8;
    for (size_t i = (size_t)blockIdx.x*256 + threadIdx.x; i < total8;
         i += (size_t)gridDim.x*256) {
        uint4 v = ((const uint4*)ybf)[i];                 // 8 bf16
        int og = (int)(i % (NOUT/8)) * 8;
        float4 o0, o1;
        o0.x = gelu_exact(__uint_as_float(v.x << 16)        * ssc[og+0] + ssh[og+0]);
        o0.y = gelu_exact(__uint_as_float(v.x & 0xffff0000u)* ssc[og+1] + ssh[og+1]);
        o0.z = gelu_exact(__uint_as_float(v.y << 16)        * ssc[og+2] + ssh[og+2]);
        o0.w = gelu_exact(__uint_as_float(v.y & 0xffff0000u)* ssc[og+3] + ssh[og+3]);
        o1.x = gelu_exact(__uint_as_float(v.z << 16)        * ssc[og+4] + ssh[og+4]);
        o1.y = gelu_exact(__uint_as_float(v.z & 0xffff0000u)* ssc[og+5] + ssh[og+5]);
        o1.z = gelu_exact(__uint_as_float(v.w << 16)        * ssc[og+6] + ssh[og+6]);
        o1.w = gelu_exact(__uint_as_float(v.w & 0xffff0000u)* ssc[og+7] + ssh[og+7]);
        ((float4*)out)[2*i]   = o0;
        ((float4*)out)[2*i+1] = o1;
    }
}

// ---------------------------------------------------------------------------
extern "C" void kernel_launch(void* const* d_in, const int* in_sizes, int n_in,
                              void* d_out, int out_size, void* d_ws, size_t ws_size,
                              hipStream_t stream)
{
    const float* x      = (const float*)d_in[0];
    const float* offw   = (const float*)d_in[1];
    const float* offb   = (const float*)d_in[2];
    const float* dconvw = (const float*)d_in[3];
    const float* gamma  = (const float*)d_in[4];
    const float* beta   = (const float*)d_in[5];
    float* out = (float*)d_out;

    const size_t NX  = (size_t)BATCH*CHW;   // 9,633,792
    const size_t NW1 = (size_t)NOFF*KDIM;   // 393,216
    const size_t NW2 = (size_t)NOUT*KDIM;   // 589,824

    unsigned short* xbf   = (unsigned short*)d_ws;
    unsigned short* wbf1  = xbf  + NX;
    unsigned short* wbf2  = wbf1 + NW1;
    unsigned short* A2    = wbf2 + NW2;                       // NPATCH*KDIM
    unsigned short* off   = A2   + (size_t)NPATCH*KDIM;       // NPATCH*NOFF
    unsigned short* ybf   = off  + (size_t)NPATCH*NOFF;       // NPATCH*NOUT
    float* fscratch = (float*)(ybf + (size_t)NPATCH*NOUT);
    float* psum  = fscratch;            // 98*768
    float* psq   = psum + NRB*NOUT;
    float* scale = psq  + NRB*NOUT;
    float* shift = scale + NOUT;

    cvt_all<<<4096, 256, 0, stream>>>(x, offw, dconvw, xbf, wbf1, wbf2);
    gemm_offsets<<<392, 256, 0, stream>>>(xbf, wbf1, offb, off);
    sampler<<<NPATCH, 256, 0, stream>>>(xbf, (const unsigned int*)off, A2);
    gemm_deform<<<588, 256, 0, stream>>>(A2, wbf2, ybf, psum, psq);
    bn_final<<<3, 256, 0, stream>>>(psum, psq, gamma, beta, scale, shift);
    norm_gelu<<<2048, 256, 0, stream>>>(ybf, out, scale, shift);
}